// Round 1
// baseline (1338.495 us; speedup 1.0000x reference)
//
#include <hip/hip_runtime.h>

#define N_TOK 2048
#define DMODEL 1024
#define NEXP 12
#define HS_DIM 2048
#define HR_DIM 3072

typedef __attribute__((ext_vector_type(8))) short bf16x8;
typedef __attribute__((ext_vector_type(4))) float f32x4;

__device__ __forceinline__ unsigned short f2bf(float x) {
  union { float f; unsigned int u; } v; v.f = x;
  unsigned int u = v.u;
  u += 0x7fff + ((u >> 16) & 1);   // round-to-nearest-even
  return (unsigned short)(u >> 16);
}
__device__ __forceinline__ float bf2f(unsigned short h) {
  union { unsigned int u; float f; } v; v.u = ((unsigned int)h) << 16; return v.f;
}
__device__ __forceinline__ float gelu_exact(float x) {
  return 0.5f * x * (1.0f + erff(x * 0.70710678118654752f));
}

// ---------------- routing ----------------

__global__ void init_kernel(int* counts, int* cursors) {
  int t = threadIdx.x;
  if (t < NEXP) { counts[t] = 0; cursors[t] = 0; }
}

__global__ __launch_bounds__(256)
void router_kernel(const float* __restrict__ X, const float* __restrict__ Wr,
                   const float* __restrict__ br, int* __restrict__ top_e,
                   float* __restrict__ top_w, int* __restrict__ counts) {
  const int wv = threadIdx.x >> 6, lane = threadIdx.x & 63;
  const int n = blockIdx.x * 4 + wv;
  float a[NEXP];
#pragma unroll
  for (int e = 0; e < NEXP; ++e) a[e] = 0.f;
  for (int it = 0; it < DMODEL / 64; ++it) {
    int k = it * 64 + lane;
    float xv = X[(size_t)n * DMODEL + k];
    const float* wr = Wr + (size_t)k * NEXP;
#pragma unroll
    for (int e = 0; e < NEXP; ++e) a[e] += xv * wr[e];
  }
#pragma unroll
  for (int e = 0; e < NEXP; ++e)
    for (int o = 32; o > 0; o >>= 1) a[e] += __shfl_xor(a[e], o, 64);
  if (lane == 0) {
    float l[NEXP];
#pragma unroll
    for (int e = 0; e < NEXP; ++e) l[e] = (a[e] + br[e]) * (1.0f / 1.5f);
    int e0 = 0;
    for (int e = 1; e < NEXP; ++e) if (l[e] > l[e0]) e0 = e;
    int e1 = (e0 == 0) ? 1 : 0;
    for (int e = 0; e < NEXP; ++e) if (e != e0 && l[e] > l[e1]) e1 = e;
    float w0 = 1.f / (1.f + __expf(l[e1] - l[e0]));
    // use precise expf for safety
    w0 = 1.f / (1.f + expf(l[e1] - l[e0]));
    top_e[n * 2 + 0] = e0; top_e[n * 2 + 1] = e1;
    top_w[n * 2 + 0] = w0; top_w[n * 2 + 1] = 1.f - w0;
    atomicAdd(&counts[e0], 1); atomicAdd(&counts[e1], 1);
  }
}

__global__ void scan_kernel(const int* __restrict__ counts, int* __restrict__ offs) {
  if (threadIdx.x == 0) {
    int s = 0;
    for (int e = 0; e < NEXP; ++e) { offs[e] = s; s += counts[e]; }
    offs[NEXP] = s;
  }
}

__global__ __launch_bounds__(256)
void fill_kernel(const int* __restrict__ top_e, const float* __restrict__ top_w,
                 const int* __restrict__ offs, int* __restrict__ cursors,
                 int* __restrict__ slot_tok, float* __restrict__ slot_w) {
  int n = blockIdx.x * 256 + threadIdx.x;
  if (n >= N_TOK) return;
#pragma unroll
  for (int j = 0; j < 2; ++j) {
    int e = top_e[n * 2 + j];
    int p = atomicAdd(&cursors[e], 1);
    int s = offs[e] + p;
    slot_tok[s] = n;
    slot_w[s] = top_w[n * 2 + j];
  }
}

// ---------------- GEMM1 + GEGLU ----------------
// C tile: 64 rows x 128 act-cols. Waves 0,1 accumulate the 'a' half,
// waves 2,3 the 'g' half (cols +H in the weight). g is activated, passed
// through LDS, multiplied into a, stored as bf16 activations.
__global__ __launch_bounds__(256)
void gemm1_geglu_kernel(const float* __restrict__ X, const float* __restrict__ W1,
                        const float* __restrict__ B1, unsigned short* __restrict__ ACT,
                        const int* __restrict__ slot_tok, const int* __restrict__ offs,
                        const int* __restrict__ counts, int H, int Mtot) {
  const int e = blockIdx.z;
  const int m0 = blockIdx.y * 64;
  const int n0 = blockIdx.x * 128;
  const int count = counts ? counts[e] : N_TOK;
  if (m0 >= count) return;
  const int off = offs ? offs[e] : 0;
  const int Wld = 2 * H;
  const float* W = W1 + (size_t)e * DMODEL * Wld;
  const float* bias = B1 + (size_t)e * Wld;

  __shared__ unsigned short As[64 * 40];
  __shared__ unsigned short Bs[2 * 128 * 40];
  __shared__ unsigned short Gs[64 * 136];

  const int t = threadIdx.x;
  // A staging: 64 rows x 32 k fp32; thread handles rows (t>>3) and (t>>3)+32, k-chunk t&7
  const int rowA = t >> 3, kcA = t & 7;
  int tok0, tok1;
  if (slot_tok) {
    int s0 = off + m0 + rowA;      if (s0 > Mtot - 1) s0 = Mtot - 1;
    int s1 = off + m0 + rowA + 32; if (s1 > Mtot - 1) s1 = Mtot - 1;
    tok0 = slot_tok[s0]; tok1 = slot_tok[s1];
  } else {
    tok0 = m0 + rowA; tok1 = m0 + rowA + 32;
  }
  const float* xr0 = X + (size_t)tok0 * DMODEL + kcA * 4;
  const float* xr1 = X + (size_t)tok1 * DMODEL + kcA * 4;

  // B staging coords: per half, 16 k-pairs x 32 col4-chunks
  const int kpB = t >> 5, c4B = t & 31;

  const int lane = t & 63, w = t >> 6;
  const int half = w >> 1, cb = w & 1;
  const int q = lane >> 4, r = lane & 15;

  f32x4 acc[4][4];
#pragma unroll
  for (int i = 0; i < 4; ++i)
#pragma unroll
    for (int j = 0; j < 4; ++j) acc[i][j] = (f32x4){0.f, 0.f, 0.f, 0.f};

  for (int kt = 0; kt < DMODEL / 32; ++kt) {
    const int k0 = kt * 32;
    __syncthreads();
    // ---- stage A (fp32 -> bf16) ----
    {
      float4 f0 = *(const float4*)(xr0 + k0);
      float4 f1 = *(const float4*)(xr1 + k0);
      uint2 p0, p1;
      p0.x = f2bf(f0.x) | ((unsigned)f2bf(f0.y) << 16);
      p0.y = f2bf(f0.z) | ((unsigned)f2bf(f0.w) << 16);
      p1.x = f2bf(f1.x) | ((unsigned)f2bf(f1.y) << 16);
      p1.y = f2bf(f1.z) | ((unsigned)f2bf(f1.w) << 16);
      *(uint2*)&As[(rowA) * 40 + kcA * 4] = p0;
      *(uint2*)&As[(rowA + 32) * 40 + kcA * 4] = p1;
    }
    // ---- stage B transposed (fp32 -> bf16), both halves ----
#pragma unroll
    for (int h = 0; h < 2; ++h) {
      const float* Wh = W + (size_t)h * H + n0 + c4B * 4;
#pragma unroll
      for (int ii = 0; ii < 2; ++ii) {
        const int kp = kpB + ii * 8;
        const float* src = Wh + (size_t)(k0 + 2 * kp) * Wld;
        float4 f0 = *(const float4*)src;
        float4 f1 = *(const float4*)(src + Wld);
        const float* a0 = (const float*)&f0;
        const float* a1 = (const float*)&f1;
#pragma unroll
        for (int j = 0; j < 4; ++j) {
          unsigned v = f2bf(a0[j]) | ((unsigned)f2bf(a1[j]) << 16);
          *(unsigned*)&Bs[(h * 128 + c4B * 4 + j) * 40 + 2 * kp] = v;
        }
      }
    }
    __syncthreads();
    // ---- compute ----
    bf16x8 aF[4], bF[4];
#pragma unroll
    for (int i = 0; i < 4; ++i)
      aF[i] = *(const bf16x8*)&As[(i * 16 + r) * 40 + q * 8];
#pragma unroll
    for (int j = 0; j < 4; ++j)
      bF[j] = *(const bf16x8*)&Bs[(half * 128 + cb * 64 + j * 16 + r) * 40 + q * 8];
#pragma unroll
    for (int i = 0; i < 4; ++i)
#pragma unroll
      for (int j = 0; j < 4; ++j)
        acc[i][j] = __builtin_amdgcn_mfma_f32_16x16x32_bf16(aF[i], bF[j], acc[i][j], 0, 0, 0);
  }

  // ---- epilogue: g-waves write gelu(g) to LDS; a-waves combine + store ----
  if (half == 1) {
#pragma unroll
    for (int i = 0; i < 4; ++i)
#pragma unroll
      for (int j = 0; j < 4; ++j)
#pragma unroll
        for (int reg = 0; reg < 4; ++reg) {
          int row = i * 16 + q * 4 + reg;
          int col = cb * 64 + j * 16 + r;
          float g = acc[i][j][reg] + bias[H + n0 + col];
          Gs[row * 136 + col] = f2bf(gelu_exact(g));
        }
  }
  __syncthreads();
  if (half == 0) {
#pragma unroll
    for (int i = 0; i < 4; ++i)
#pragma unroll
      for (int j = 0; j < 4; ++j)
#pragma unroll
        for (int reg = 0; reg < 4; ++reg) {
          int row = i * 16 + q * 4 + reg;
          int col = cb * 64 + j * 16 + r;
          if (m0 + row < count) {
            float a = acc[i][j][reg] + bias[n0 + col];
            float gv = bf2f(Gs[row * 136 + col]);
            ACT[(size_t)(off + m0 + row) * H + n0 + col] = f2bf(a * gv);
          }
        }
  }
}

// ---------------- GEMM2 ----------------
// 128x128 tile. A = bf16 activations, B = fp32 W2 converted in staging.
// Shared: plain store (out = ys + bias). Routed: atomicAdd(w_slot*(acc+bias)).
__global__ __launch_bounds__(256)
void gemm2_kernel(const unsigned short* __restrict__ ACT, const float* __restrict__ W2,
                  const float* __restrict__ B2, float* __restrict__ OUT,
                  const int* __restrict__ slot_tok, const float* __restrict__ slot_w,
                  const int* __restrict__ offs, const int* __restrict__ counts,
                  int K, int Mtot) {
  const int e = blockIdx.z;
  const int m0 = blockIdx.y * 128;
  const int n0 = blockIdx.x * 128;
  const int count = counts ? counts[e] : N_TOK;
  if (m0 >= count) return;
  const int off = offs ? offs[e] : 0;
  const float* W = W2 + (size_t)e * K * DMODEL;
  const float* bias = B2 + (size_t)e * DMODEL;

  __shared__ unsigned short As[128 * 40];
  __shared__ unsigned short Bs[128 * 40];

  const int t = threadIdx.x;
  const int rowA = t >> 2, kcA = t & 3;   // rows rowA and rowA+64, 8-elt chunk kcA
  int s0 = off + m0 + rowA, s1 = off + m0 + rowA + 64;
  if (s0 > Mtot - 1) s0 = Mtot - 1;
  if (s1 > Mtot - 1) s1 = Mtot - 1;
  const unsigned short* ar0 = ACT + (size_t)s0 * K + kcA * 8;
  const unsigned short* ar1 = ACT + (size_t)s1 * K + kcA * 8;

  const int kpB = t >> 5, c4B = t & 31;

  const int lane = t & 63, w = t >> 6;
  const int wrow = (w >> 1) * 64, wcol = (w & 1) * 64;
  const int q = lane >> 4, r = lane & 15;

  f32x4 acc[4][4];
#pragma unroll
  for (int i = 0; i < 4; ++i)
#pragma unroll
    for (int j = 0; j < 4; ++j) acc[i][j] = (f32x4){0.f, 0.f, 0.f, 0.f};

  const int KT = K >> 5;
  for (int kt = 0; kt < KT; ++kt) {
    const int k0 = kt * 32;
    __syncthreads();
    // A: already bf16, straight 16B copies
    *(uint4*)&As[rowA * 40 + kcA * 8] = *(const uint4*)(ar0 + k0);
    *(uint4*)&As[(rowA + 64) * 40 + kcA * 8] = *(const uint4*)(ar1 + k0);
    // B: fp32 -> bf16 transposed
#pragma unroll
    for (int ii = 0; ii < 2; ++ii) {
      const int kp = kpB + ii * 8;
      const float* src = W + (size_t)(k0 + 2 * kp) * DMODEL + n0 + c4B * 4;
      float4 f0 = *(const float4*)src;
      float4 f1 = *(const float4*)(src + DMODEL);
      const float* a0 = (const float*)&f0;
      const float* a1 = (const float*)&f1;
#pragma unroll
      for (int j = 0; j < 4; ++j) {
        unsigned v = f2bf(a0[j]) | ((unsigned)f2bf(a1[j]) << 16);
        *(unsigned*)&Bs[(c4B * 4 + j) * 40 + 2 * kp] = v;
      }
    }
    __syncthreads();
    bf16x8 aF[4], bF[4];
#pragma unroll
    for (int i = 0; i < 4; ++i)
      aF[i] = *(const bf16x8*)&As[(wrow + i * 16 + r) * 40 + q * 8];
#pragma unroll
    for (int j = 0; j < 4; ++j)
      bF[j] = *(const bf16x8*)&Bs[(wcol + j * 16 + r) * 40 + q * 8];
#pragma unroll
    for (int i = 0; i < 4; ++i)
#pragma unroll
      for (int j = 0; j < 4; ++j)
        acc[i][j] = __builtin_amdgcn_mfma_f32_16x16x32_bf16(aF[i], bF[j], acc[i][j], 0, 0, 0);
  }

#pragma unroll
  for (int i = 0; i < 4; ++i)
#pragma unroll
    for (int j = 0; j < 4; ++j)
#pragma unroll
      for (int reg = 0; reg < 4; ++reg) {
        int row = wrow + i * 16 + q * 4 + reg;
        int col = wcol + j * 16 + r;
        if (m0 + row < count) {
          float v = acc[i][j][reg] + bias[n0 + col];
          if (slot_tok) {
            int s = off + m0 + row;
            atomicAdd(&OUT[(size_t)slot_tok[s] * DMODEL + n0 + col], slot_w[s] * v);
          } else {
            OUT[(size_t)(m0 + row) * DMODEL + n0 + col] = v;
          }
        }
      }
}

// ---------------- launch ----------------

extern "C" void kernel_launch(void* const* d_in, const int* in_sizes, int n_in,
                              void* d_out, int out_size, void* d_ws, size_t ws_size,
                              hipStream_t stream) {
  const float* x   = (const float*)d_in[0];
  const float* Ws1 = (const float*)d_in[1];
  const float* bs1 = (const float*)d_in[2];
  const float* Ws2 = (const float*)d_in[3];
  const float* bs2 = (const float*)d_in[4];
  const float* We1 = (const float*)d_in[5];
  const float* be1 = (const float*)d_in[6];
  const float* We2 = (const float*)d_in[7];
  const float* be2 = (const float*)d_in[8];
  const float* Wr  = (const float*)d_in[9];
  const float* br  = (const float*)d_in[10];
  float* out = (float*)d_out;

  char* p = (char*)d_ws;
  int* counts  = (int*)p; p += 256;
  int* cursors = (int*)p; p += 256;
  int* offs    = (int*)p; p += 256;
  int* top_e   = (int*)p; p += (size_t)N_TOK * 2 * 4;
  float* top_w = (float*)p; p += (size_t)N_TOK * 2 * 4;
  int* slot_tok = (int*)p; p += (size_t)2 * N_TOK * 4;
  float* slot_w = (float*)p; p += (size_t)2 * N_TOK * 4;
  unsigned short* act_s = (unsigned short*)p; p += (size_t)N_TOK * HS_DIM * 2;
  unsigned short* act_r = (unsigned short*)p; p += (size_t)2 * N_TOK * HR_DIM * 2;

  init_kernel<<<1, 64, 0, stream>>>(counts, cursors);
  router_kernel<<<N_TOK / 4, 256, 0, stream>>>(x, Wr, br, top_e, top_w, counts);
  scan_kernel<<<1, 64, 0, stream>>>(counts, offs);
  fill_kernel<<<N_TOK / 256, 256, 0, stream>>>(top_e, top_w, offs, cursors, slot_tok, slot_w);

  // shared expert GEMM1+GEGLU: H=2048, M=2048
  gemm1_geglu_kernel<<<dim3(HS_DIM / 128, N_TOK / 64, 1), 256, 0, stream>>>(
      x, Ws1, bs1, act_s, nullptr, nullptr, nullptr, HS_DIM, N_TOK);
  // routed GEMM1+GEGLU: H=3072, gathered rows
  gemm1_geglu_kernel<<<dim3(HR_DIM / 128, N_TOK / 64, NEXP), 256, 0, stream>>>(
      x, We1, be1, act_r, slot_tok, offs, counts, HR_DIM, 2 * N_TOK);
  // shared GEMM2 -> writes out (ys)
  gemm2_kernel<<<dim3(DMODEL / 128, N_TOK / 128, 1), 256, 0, stream>>>(
      act_s, Ws2, bs2, out, nullptr, nullptr, nullptr, nullptr, HS_DIM, N_TOK);
  // routed GEMM2 -> atomically adds w*(actW2+b2)
  gemm2_kernel<<<dim3(DMODEL / 128, N_TOK / 128, NEXP), 256, 0, stream>>>(
      act_r, We2, be2, out, slot_tok, slot_w, offs, counts, HR_DIM, 2 * N_TOK);
}

// Round 2
// 1030.025 us; speedup vs baseline: 1.2995x; 1.2995x over previous
//
#include <hip/hip_runtime.h>

#define N_TOK 2048
#define DMODEL 1024
#define NEXP 12
#define HS_DIM 2048
#define HR_DIM 3072

typedef __attribute__((ext_vector_type(8))) short bf16x8;
typedef __attribute__((ext_vector_type(4))) float f32x4;

#define AS1 __attribute__((address_space(1)))
#define AS3 __attribute__((address_space(3)))

__device__ __forceinline__ void gl_lds16(const void* g, void* l) {
  __builtin_amdgcn_global_load_lds((const AS1 void*)g, (AS3 void*)l, 16, 0, 0);
}

__device__ __forceinline__ unsigned short f2bf(float x) {
  union { float f; unsigned int u; } v; v.f = x;
  unsigned int u = v.u;
  u += 0x7fff + ((u >> 16) & 1);   // round-to-nearest-even
  return (unsigned short)(u >> 16);
}
__device__ __forceinline__ unsigned pack2(float a, float b) {
  return (unsigned)f2bf(a) | ((unsigned)f2bf(b) << 16);
}
__device__ __forceinline__ float gelu_exact(float x) {
  return 0.5f * x * (1.0f + erff(x * 0.70710678118654752f));
}

// ---------------- pre-pass: fp32 -> bf16 conversions ----------------

// x [N_TOK, D] fp32 -> bf16, flat
__global__ __launch_bounds__(256)
void convert_x_kernel(const float* __restrict__ X, unsigned short* __restrict__ XB) {
  const int idx = (blockIdx.x * 256 + threadIdx.x) * 8;
  float4 f0 = *(const float4*)(X + idx);
  float4 f1 = *(const float4*)(X + idx + 4);
  uint4 o;
  o.x = pack2(f0.x, f0.y); o.y = pack2(f0.z, f0.w);
  o.z = pack2(f1.x, f1.y); o.w = pack2(f1.z, f1.w);
  *(uint4*)(XB + idx) = o;
}

// W [batch][K][N] fp32 -> WT [batch][N][K] bf16.  64x64 tiles via LDS.
__global__ __launch_bounds__(256)
void tconv_kernel(const float* __restrict__ W, unsigned short* __restrict__ WT,
                  int K, int N) {
  const int n0 = blockIdx.x * 64;
  const int k0 = blockIdx.y * 64;
  const size_t bo = (size_t)blockIdx.z * K * N;
  __shared__ unsigned short Ts[64 * 72];
  const int t = threadIdx.x;
  // phase 1: load 4x4 fp32 sub-block (rows k, cols n), store transposed bf16
  const int k4 = (t >> 4) * 4, n4 = (t & 15) * 4;
  float4 rw[4];
#pragma unroll
  for (int i = 0; i < 4; ++i)
    rw[i] = *(const float4*)(W + bo + (size_t)(k0 + k4 + i) * N + n0 + n4);
#pragma unroll
  for (int j = 0; j < 4; ++j) {
    uint2 v;
    v.x = pack2(((const float*)&rw[0])[j], ((const float*)&rw[1])[j]);
    v.y = pack2(((const float*)&rw[2])[j], ((const float*)&rw[3])[j]);
    *(uint2*)&Ts[(n4 + j) * 72 + k4] = v;
  }
  __syncthreads();
  // phase 2: vector-read rows of Ts (n fixed, k contiguous), store coalesced
  const int n = t >> 2, kc = (t & 3) * 16;
  uint4 v0 = *(const uint4*)&Ts[n * 72 + kc];
  uint4 v1 = *(const uint4*)&Ts[n * 72 + kc + 8];
  unsigned short* dst = WT + (size_t)blockIdx.z * N * K + (size_t)(n0 + n) * K + k0 + kc;
  *(uint4*)dst = v0;
  *(uint4*)(dst + 8) = v1;
}

// ---------------- routing ----------------

__global__ void init_kernel(int* counts, int* cursors) {
  int t = threadIdx.x;
  if (t < NEXP) { counts[t] = 0; cursors[t] = 0; }
}

__global__ __launch_bounds__(256)
void router_kernel(const float* __restrict__ X, const float* __restrict__ Wr,
                   const float* __restrict__ br, int* __restrict__ top_e,
                   float* __restrict__ top_w, int* __restrict__ counts) {
  const int wv = threadIdx.x >> 6, lane = threadIdx.x & 63;
  const int n = blockIdx.x * 4 + wv;
  float a[NEXP];
#pragma unroll
  for (int e = 0; e < NEXP; ++e) a[e] = 0.f;
  for (int it = 0; it < DMODEL / 64; ++it) {
    int k = it * 64 + lane;
    float xv = X[(size_t)n * DMODEL + k];
    const float* wr = Wr + (size_t)k * NEXP;
#pragma unroll
    for (int e = 0; e < NEXP; ++e) a[e] += xv * wr[e];
  }
#pragma unroll
  for (int e = 0; e < NEXP; ++e)
    for (int o = 32; o > 0; o >>= 1) a[e] += __shfl_xor(a[e], o, 64);
  if (lane == 0) {
    float l[NEXP];
#pragma unroll
    for (int e = 0; e < NEXP; ++e) l[e] = (a[e] + br[e]) * (1.0f / 1.5f);
    int e0 = 0;
    for (int e = 1; e < NEXP; ++e) if (l[e] > l[e0]) e0 = e;
    int e1 = (e0 == 0) ? 1 : 0;
    for (int e = 0; e < NEXP; ++e) if (e != e0 && l[e] > l[e1]) e1 = e;
    float w0 = 1.f / (1.f + expf(l[e1] - l[e0]));
    top_e[n * 2 + 0] = e0; top_e[n * 2 + 1] = e1;
    top_w[n * 2 + 0] = w0; top_w[n * 2 + 1] = 1.f - w0;
    atomicAdd(&counts[e0], 1); atomicAdd(&counts[e1], 1);
  }
}

__global__ void scan_kernel(const int* __restrict__ counts, int* __restrict__ offs) {
  if (threadIdx.x == 0) {
    int s = 0;
    for (int e = 0; e < NEXP; ++e) { offs[e] = s; s += counts[e]; }
    offs[NEXP] = s;
  }
}

__global__ __launch_bounds__(256)
void fill_kernel(const int* __restrict__ top_e, const float* __restrict__ top_w,
                 const int* __restrict__ offs, int* __restrict__ cursors,
                 int* __restrict__ slot_tok, float* __restrict__ slot_w) {
  int n = blockIdx.x * 256 + threadIdx.x;
  if (n >= N_TOK) return;
#pragma unroll
  for (int j = 0; j < 2; ++j) {
    int e = top_e[n * 2 + j];
    int p = atomicAdd(&cursors[e], 1);
    int s = offs[e] + p;
    slot_tok[s] = n;
    slot_w[s] = top_w[n * 2 + j];
  }
}

// ---------------- GEMM1 + GEGLU (all-bf16, global_load_lds) ----------------
// Tile: 128 rows x 128 act-cols; B panel = 256 W1T rows (a-cols then g-cols).
// Each wave owns 64x64 of BOTH a and g; GEGLU combined in-register.
__global__ __launch_bounds__(256, 2)
void gemm1_kernel(const unsigned short* __restrict__ XB,
                  const unsigned short* __restrict__ W1T,
                  const float* __restrict__ B1, unsigned short* __restrict__ ACT,
                  const int* __restrict__ slot_tok, const int* __restrict__ offs,
                  const int* __restrict__ counts, int H, int Mtot) {
  const int e = blockIdx.z;
  const int n0 = blockIdx.x * 128;
  const int m0 = blockIdx.y * 128;
  const int count = counts ? counts[e] : N_TOK;
  if (m0 >= count) return;
  const int off = offs ? offs[e] : 0;
  const unsigned short* W = W1T + (size_t)e * 2 * H * DMODEL;
  const float* bias = B1 + (size_t)e * 2 * H;

  __shared__ unsigned short As[128 * 32];   // 8 KB, rows k-contig, no pad
  __shared__ unsigned short Bs[256 * 32];   // 16 KB

  const int t = threadIdx.x;
  const int lane = t & 63, wv = t >> 6;
  const int srow = t >> 2, skc = t & 3;

  // A source rows srow, srow+64 (gathered for routed)
  int r0 = m0 + srow, r1 = m0 + srow + 64;
  if (slot_tok) {
    int s0 = off + r0; if (s0 >= Mtot) s0 = Mtot - 1;
    int s1 = off + r1; if (s1 >= Mtot) s1 = Mtot - 1;
    r0 = slot_tok[s0]; r1 = slot_tok[s1];
  }
  const unsigned short* ap0 = XB + (size_t)r0 * DMODEL + skc * 8;
  const unsigned short* ap1 = XB + (size_t)r1 * DMODEL + skc * 8;
  const unsigned short* bp[4];
#pragma unroll
  for (int ii = 0; ii < 4; ++ii) {
    int brow = srow + 64 * ii;
    int wrow = (brow < 128) ? (n0 + brow) : (H + n0 + brow - 128);
    bp[ii] = W + (size_t)wrow * DMODEL + skc * 8;
  }
  unsigned short* aL0 = &As[wv * 512];
  unsigned short* aL1 = &As[2048 + wv * 512];
  unsigned short* bL0 = &Bs[wv * 512];
  unsigned short* bL1 = &Bs[2048 + wv * 512];
  unsigned short* bL2 = &Bs[4096 + wv * 512];
  unsigned short* bL3 = &Bs[6144 + wv * 512];

  const int q = lane >> 4, rr = lane & 15;
  const int wr = wv >> 1, wc = wv & 1;

  f32x4 acc_a[4][4], acc_g[4][4];
#pragma unroll
  for (int i = 0; i < 4; ++i)
#pragma unroll
    for (int j = 0; j < 4; ++j) {
      acc_a[i][j] = (f32x4){0.f, 0.f, 0.f, 0.f};
      acc_g[i][j] = (f32x4){0.f, 0.f, 0.f, 0.f};
    }

  for (int kt = 0; kt < DMODEL / 32; ++kt) {
    const int kb = kt * 32;
    __syncthreads();
    gl_lds16(ap0 + kb, aL0);
    gl_lds16(ap1 + kb, aL1);
    gl_lds16(bp[0] + kb, bL0);
    gl_lds16(bp[1] + kb, bL1);
    gl_lds16(bp[2] + kb, bL2);
    gl_lds16(bp[3] + kb, bL3);
    __syncthreads();
    bf16x8 aF[4], bA[4], bG[4];
#pragma unroll
    for (int i = 0; i < 4; ++i)
      aF[i] = *(const bf16x8*)&As[(wr * 64 + i * 16 + rr) * 32 + q * 8];
#pragma unroll
    for (int j = 0; j < 4; ++j) {
      bA[j] = *(const bf16x8*)&Bs[(wc * 64 + j * 16 + rr) * 32 + q * 8];
      bG[j] = *(const bf16x8*)&Bs[(128 + wc * 64 + j * 16 + rr) * 32 + q * 8];
    }
#pragma unroll
    for (int i = 0; i < 4; ++i)
#pragma unroll
      for (int j = 0; j < 4; ++j) {
        acc_a[i][j] = __builtin_amdgcn_mfma_f32_16x16x32_bf16(aF[i], bA[j], acc_a[i][j], 0, 0, 0);
        acc_g[i][j] = __builtin_amdgcn_mfma_f32_16x16x32_bf16(aF[i], bG[j], acc_g[i][j], 0, 0, 0);
      }
  }

  float ba[4], bg[4];
#pragma unroll
  for (int j = 0; j < 4; ++j) {
    int col = wc * 64 + j * 16 + rr;
    ba[j] = bias[n0 + col];
    bg[j] = bias[H + n0 + col];
  }
#pragma unroll
  for (int i = 0; i < 4; ++i)
#pragma unroll
    for (int j = 0; j < 4; ++j)
#pragma unroll
      for (int reg = 0; reg < 4; ++reg) {
        int row = wr * 64 + i * 16 + q * 4 + reg;
        if (m0 + row < count) {
          int col = wc * 64 + j * 16 + rr;
          float av = acc_a[i][j][reg] + ba[j];
          float gv = acc_g[i][j][reg] + bg[j];
          ACT[(size_t)(off + m0 + row) * H + n0 + col] = f2bf(av * gelu_exact(gv));
        }
      }
}

// ---------------- GEMM2 (all-bf16, global_load_lds) ----------------
__global__ __launch_bounds__(256, 2)
void gemm2_kernel(const unsigned short* __restrict__ ACT,
                  const unsigned short* __restrict__ W2T,
                  const float* __restrict__ B2, float* __restrict__ OUT,
                  const int* __restrict__ slot_tok, const float* __restrict__ slot_w,
                  const int* __restrict__ offs, const int* __restrict__ counts,
                  int K, int Mtot) {
  const int e = blockIdx.z;
  const int n0 = blockIdx.x * 128;
  const int m0 = blockIdx.y * 128;
  const int count = counts ? counts[e] : N_TOK;
  if (m0 >= count) return;
  const int off = offs ? offs[e] : 0;
  const unsigned short* W = W2T + (size_t)e * DMODEL * K;
  const float* bias = B2 + (size_t)e * DMODEL;

  __shared__ unsigned short As[128 * 32];
  __shared__ unsigned short Bs[128 * 32];

  const int t = threadIdx.x;
  const int lane = t & 63, wv = t >> 6;
  const int srow = t >> 2, skc = t & 3;

  int s0 = off + m0 + srow;      if (s0 >= Mtot) s0 = Mtot - 1;
  int s1 = off + m0 + srow + 64; if (s1 >= Mtot) s1 = Mtot - 1;
  const unsigned short* ap0 = ACT + (size_t)s0 * K + skc * 8;
  const unsigned short* ap1 = ACT + (size_t)s1 * K + skc * 8;
  const unsigned short* bp0 = W + (size_t)(n0 + srow) * K + skc * 8;
  const unsigned short* bp1 = W + (size_t)(n0 + srow + 64) * K + skc * 8;

  unsigned short* aL0 = &As[wv * 512];
  unsigned short* aL1 = &As[2048 + wv * 512];
  unsigned short* bL0 = &Bs[wv * 512];
  unsigned short* bL1 = &Bs[2048 + wv * 512];

  const int q = lane >> 4, rr = lane & 15;
  const int wr = wv >> 1, wc = wv & 1;

  f32x4 acc[4][4];
#pragma unroll
  for (int i = 0; i < 4; ++i)
#pragma unroll
    for (int j = 0; j < 4; ++j) acc[i][j] = (f32x4){0.f, 0.f, 0.f, 0.f};

  const int KT = K >> 5;
  for (int kt = 0; kt < KT; ++kt) {
    const int kb = kt * 32;
    __syncthreads();
    gl_lds16(ap0 + kb, aL0);
    gl_lds16(ap1 + kb, aL1);
    gl_lds16(bp0 + kb, bL0);
    gl_lds16(bp1 + kb, bL1);
    __syncthreads();
    bf16x8 aF[4], bF[4];
#pragma unroll
    for (int i = 0; i < 4; ++i)
      aF[i] = *(const bf16x8*)&As[(wr * 64 + i * 16 + rr) * 32 + q * 8];
#pragma unroll
    for (int j = 0; j < 4; ++j)
      bF[j] = *(const bf16x8*)&Bs[(wc * 64 + j * 16 + rr) * 32 + q * 8];
#pragma unroll
    for (int i = 0; i < 4; ++i)
#pragma unroll
      for (int j = 0; j < 4; ++j)
        acc[i][j] = __builtin_amdgcn_mfma_f32_16x16x32_bf16(aF[i], bF[j], acc[i][j], 0, 0, 0);
  }

  float bb[4];
#pragma unroll
  for (int j = 0; j < 4; ++j) bb[j] = bias[n0 + wc * 64 + j * 16 + rr];
#pragma unroll
  for (int i = 0; i < 4; ++i)
#pragma unroll
    for (int j = 0; j < 4; ++j)
#pragma unroll
      for (int reg = 0; reg < 4; ++reg) {
        int row = wr * 64 + i * 16 + q * 4 + reg;
        if (m0 + row < count) {
          int col = wc * 64 + j * 16 + rr;
          float v = acc[i][j][reg] + bb[j];
          if (slot_tok) {
            int s = off + m0 + row;
            atomicAdd(&OUT[(size_t)slot_tok[s] * DMODEL + n0 + col], slot_w[s] * v);
          } else {
            OUT[(size_t)(m0 + row) * DMODEL + n0 + col] = v;
          }
        }
      }
}

// ---------------- launch ----------------
// Workspace budget (~280 MB):
//   misc ~64KB | xb 4MB | ws1t 8MB | ws2t 4MB | we1t 151MB | we2t 75.5MB
//   act_s 8MB | act_r 25.2MB

extern "C" void kernel_launch(void* const* d_in, const int* in_sizes, int n_in,
                              void* d_out, int out_size, void* d_ws, size_t ws_size,
                              hipStream_t stream) {
  const float* x   = (const float*)d_in[0];
  const float* Ws1 = (const float*)d_in[1];
  const float* bs1 = (const float*)d_in[2];
  const float* Ws2 = (const float*)d_in[3];
  const float* bs2 = (const float*)d_in[4];
  const float* We1 = (const float*)d_in[5];
  const float* be1 = (const float*)d_in[6];
  const float* We2 = (const float*)d_in[7];
  const float* be2 = (const float*)d_in[8];
  const float* Wr  = (const float*)d_in[9];
  const float* br  = (const float*)d_in[10];
  float* out = (float*)d_out;

  char* p = (char*)d_ws;
  int* counts  = (int*)p; p += 256;
  int* cursors = (int*)p; p += 256;
  int* offs    = (int*)p; p += 256;
  int* top_e   = (int*)p; p += (size_t)N_TOK * 2 * 4;
  float* top_w = (float*)p; p += (size_t)N_TOK * 2 * 4;
  int* slot_tok = (int*)p; p += (size_t)2 * N_TOK * 4;
  float* slot_w = (float*)p; p += (size_t)2 * N_TOK * 4;
  unsigned short* xb    = (unsigned short*)p; p += (size_t)N_TOK * DMODEL * 2;
  unsigned short* ws1t  = (unsigned short*)p; p += (size_t)2 * HS_DIM * DMODEL * 2;
  unsigned short* ws2t  = (unsigned short*)p; p += (size_t)DMODEL * HS_DIM * 2;
  unsigned short* we1t  = (unsigned short*)p; p += (size_t)NEXP * 2 * HR_DIM * DMODEL * 2;
  unsigned short* we2t  = (unsigned short*)p; p += (size_t)NEXP * DMODEL * HR_DIM * 2;
  unsigned short* act_s = (unsigned short*)p; p += (size_t)N_TOK * HS_DIM * 2;
  unsigned short* act_r = (unsigned short*)p; p += (size_t)2 * N_TOK * HR_DIM * 2;

  // routing chain
  init_kernel<<<1, 64, 0, stream>>>(counts, cursors);
  router_kernel<<<N_TOK / 4, 256, 0, stream>>>(x, Wr, br, top_e, top_w, counts);
  scan_kernel<<<1, 64, 0, stream>>>(counts, offs);
  fill_kernel<<<N_TOK / 256, 256, 0, stream>>>(top_e, top_w, offs, cursors, slot_tok, slot_w);

  // conversions
  convert_x_kernel<<<(N_TOK * DMODEL) / 2048, 256, 0, stream>>>(x, xb);
  tconv_kernel<<<dim3(2 * HS_DIM / 64, DMODEL / 64, 1), 256, 0, stream>>>(Ws1, ws1t, DMODEL, 2 * HS_DIM);
  tconv_kernel<<<dim3(DMODEL / 64, HS_DIM / 64, 1), 256, 0, stream>>>(Ws2, ws2t, HS_DIM, DMODEL);
  tconv_kernel<<<dim3(2 * HR_DIM / 64, DMODEL / 64, NEXP), 256, 0, stream>>>(We1, we1t, DMODEL, 2 * HR_DIM);
  tconv_kernel<<<dim3(DMODEL / 64, HR_DIM / 64, NEXP), 256, 0, stream>>>(We2, we2t, HR_DIM, DMODEL);

  // GEMM1 + GEGLU
  gemm1_kernel<<<dim3(HS_DIM / 128, N_TOK / 128, 1), 256, 0, stream>>>(
      xb, ws1t, bs1, act_s, nullptr, nullptr, nullptr, HS_DIM, N_TOK);
  gemm1_kernel<<<dim3(HR_DIM / 128, N_TOK / 128, NEXP), 256, 0, stream>>>(
      xb, we1t, be1, act_r, slot_tok, offs, counts, HR_DIM, 2 * N_TOK);

  // GEMM2: shared writes out, routed atomically accumulates (stream-ordered)
  gemm2_kernel<<<dim3(DMODEL / 128, N_TOK / 128, 1), 256, 0, stream>>>(
      act_s, ws2t, bs2, out, nullptr, nullptr, nullptr, nullptr, HS_DIM, N_TOK);
  gemm2_kernel<<<dim3(DMODEL / 128, N_TOK / 128, NEXP), 256, 0, stream>>>(
      act_r, we2t, be2, out, slot_tok, slot_w, offs, counts, HR_DIM, 2 * N_TOK);
}

// Round 3
// 967.568 us; speedup vs baseline: 1.3834x; 1.0646x over previous
//
#include <hip/hip_runtime.h>

#define N_TOK 2048
#define DMODEL 1024
#define NEXP 12
#define HS_DIM 2048
#define HR_DIM 3072

typedef __attribute__((ext_vector_type(8))) short bf16x8;
typedef __attribute__((ext_vector_type(16))) float f32x16;

#define AS1 __attribute__((address_space(1)))
#define AS3 __attribute__((address_space(3)))

__device__ __forceinline__ void gl_lds16(const void* g, void* l) {
  __builtin_amdgcn_global_load_lds((const AS1 void*)g, (AS3 void*)l, 16, 0, 0);
}

__device__ __forceinline__ unsigned short f2bf(float x) {
  union { float f; unsigned int u; } v; v.f = x;
  unsigned int u = v.u;
  u += 0x7fff + ((u >> 16) & 1);   // round-to-nearest-even
  return (unsigned short)(u >> 16);
}
__device__ __forceinline__ unsigned pack2(float a, float b) {
  return (unsigned)f2bf(a) | ((unsigned)f2bf(b) << 16);
}
__device__ __forceinline__ float gelu_exact(float x) {
  return 0.5f * x * (1.0f + erff(x * 0.70710678118654752f));
}

// ---------------- pre-pass: fp32 -> bf16 conversions ----------------

__global__ __launch_bounds__(256)
void convert_x_kernel(const float* __restrict__ X, unsigned short* __restrict__ XB) {
  const int idx = (blockIdx.x * 256 + threadIdx.x) * 8;
  float4 f0 = *(const float4*)(X + idx);
  float4 f1 = *(const float4*)(X + idx + 4);
  uint4 o;
  o.x = pack2(f0.x, f0.y); o.y = pack2(f0.z, f0.w);
  o.z = pack2(f1.x, f1.y); o.w = pack2(f1.z, f1.w);
  *(uint4*)(XB + idx) = o;
}

// W [batch][K][N] fp32 -> WT [batch][N][K] bf16.  64x64 tiles via LDS.
__global__ __launch_bounds__(256)
void tconv_kernel(const float* __restrict__ W, unsigned short* __restrict__ WT,
                  int K, int N) {
  const int n0 = blockIdx.x * 64;
  const int k0 = blockIdx.y * 64;
  const size_t bo = (size_t)blockIdx.z * K * N;
  __shared__ __align__(16) unsigned short Ts[64 * 72];
  const int t = threadIdx.x;
  const int k4 = (t >> 4) * 4, n4 = (t & 15) * 4;
  float4 rw[4];
#pragma unroll
  for (int i = 0; i < 4; ++i)
    rw[i] = *(const float4*)(W + bo + (size_t)(k0 + k4 + i) * N + n0 + n4);
#pragma unroll
  for (int j = 0; j < 4; ++j) {
    uint2 v;
    v.x = pack2(((const float*)&rw[0])[j], ((const float*)&rw[1])[j]);
    v.y = pack2(((const float*)&rw[2])[j], ((const float*)&rw[3])[j]);
    *(uint2*)&Ts[(n4 + j) * 72 + k4] = v;
  }
  __syncthreads();
  const int n = t >> 2, kc = (t & 3) * 16;
  uint4 v0 = *(const uint4*)&Ts[n * 72 + kc];
  uint4 v1 = *(const uint4*)&Ts[n * 72 + kc + 8];
  unsigned short* dst = WT + (size_t)blockIdx.z * N * K + (size_t)(n0 + n) * K + k0 + kc;
  *(uint4*)dst = v0;
  *(uint4*)(dst + 8) = v1;
}

// ---------------- routing ----------------

__global__ void init_kernel(int* counts, int* cursors) {
  int t = threadIdx.x;
  if (t < NEXP) { counts[t] = 0; cursors[t] = 0; }
}

__global__ __launch_bounds__(256)
void router_kernel(const float* __restrict__ X, const float* __restrict__ Wr,
                   const float* __restrict__ br, int* __restrict__ top_e,
                   float* __restrict__ top_w, int* __restrict__ counts) {
  const int wv = threadIdx.x >> 6, lane = threadIdx.x & 63;
  const int n = blockIdx.x * 4 + wv;
  float a[NEXP];
#pragma unroll
  for (int e = 0; e < NEXP; ++e) a[e] = 0.f;
  for (int it = 0; it < DMODEL / 64; ++it) {
    int k = it * 64 + lane;
    float xv = X[(size_t)n * DMODEL + k];
    const float* wr = Wr + (size_t)k * NEXP;
#pragma unroll
    for (int e = 0; e < NEXP; ++e) a[e] += xv * wr[e];
  }
#pragma unroll
  for (int e = 0; e < NEXP; ++e)
    for (int o = 32; o > 0; o >>= 1) a[e] += __shfl_xor(a[e], o, 64);
  if (lane == 0) {
    float l[NEXP];
#pragma unroll
    for (int e = 0; e < NEXP; ++e) l[e] = (a[e] + br[e]) * (1.0f / 1.5f);
    int e0 = 0;
    for (int e = 1; e < NEXP; ++e) if (l[e] > l[e0]) e0 = e;
    int e1 = (e0 == 0) ? 1 : 0;
    for (int e = 0; e < NEXP; ++e) if (e != e0 && l[e] > l[e1]) e1 = e;
    float w0 = 1.f / (1.f + expf(l[e1] - l[e0]));
    top_e[n * 2 + 0] = e0; top_e[n * 2 + 1] = e1;
    top_w[n * 2 + 0] = w0; top_w[n * 2 + 1] = 1.f - w0;
    atomicAdd(&counts[e0], 1); atomicAdd(&counts[e1], 1);
  }
}

__global__ void scan_kernel(const int* __restrict__ counts, int* __restrict__ offs) {
  if (threadIdx.x == 0) {
    int s = 0;
    for (int e = 0; e < NEXP; ++e) { offs[e] = s; s += counts[e]; }
    offs[NEXP] = s;
  }
}

__global__ __launch_bounds__(256)
void fill_kernel(const int* __restrict__ top_e, const float* __restrict__ top_w,
                 const int* __restrict__ offs, int* __restrict__ cursors,
                 int* __restrict__ slot_tok, float* __restrict__ slot_w) {
  int n = blockIdx.x * 256 + threadIdx.x;
  if (n >= N_TOK) return;
#pragma unroll
  for (int j = 0; j < 2; ++j) {
    int e = top_e[n * 2 + j];
    int p = atomicAdd(&cursors[e], 1);
    int s = offs[e] + p;
    slot_tok[s] = n;
    slot_w[s] = top_w[n * 2 + j];
  }
}

__global__ __launch_bounds__(256)
void zero_out_kernel(float4* __restrict__ out) {
  out[blockIdx.x * 256 + threadIdx.x] = make_float4(0.f, 0.f, 0.f, 0.f);
}

// ---------------- GEMM1 + GEGLU, single launch (shared + all experts) ----
// BM=128, BN=128 act-cols (B panel = 256 rows: a-cols then g-cols).
// BK=64 as two contiguous BK=32 sub-buffers. mfma_f32_32x32x16_bf16.
// Wave owns 64x64 of both a and g; GEGLU in-register.
#define G1_SHARED 256   /* 16 m x 16 n */
#define G1_PER_E  384   /* 16 m x 24 n */

__global__ __launch_bounds__(256, 2)
void gemm1_all_kernel(const unsigned short* __restrict__ XB,
                      const unsigned short* __restrict__ WS,
                      const unsigned short* __restrict__ WE,
                      const float* __restrict__ BSb, const float* __restrict__ BEb,
                      unsigned short* __restrict__ ACT_S, unsigned short* __restrict__ ACT_R,
                      const int* __restrict__ slot_tok, const int* __restrict__ offs,
                      const int* __restrict__ counts) {
  int id = blockIdx.x;
  const unsigned short* W; const float* bias; unsigned short* ACT;
  int H, count, off, m0, n0, routed;
  if (id < G1_SHARED) {
    routed = 0;
    m0 = (id >> 4) * 128; n0 = (id & 15) * 128;
    W = WS; bias = BSb; ACT = ACT_S; H = HS_DIM; count = N_TOK; off = 0;
  } else {
    routed = 1;
    id -= G1_SHARED;
    const int e = id / G1_PER_E, rem = id % G1_PER_E;
    m0 = (rem / 24) * 128; n0 = (rem % 24) * 128;
    W = WE + (size_t)e * 2 * HR_DIM * DMODEL;
    bias = BEb + (size_t)e * 2 * HR_DIM;
    ACT = ACT_R; H = HR_DIM; count = counts[e]; off = offs[e];
  }
  if (m0 >= count) return;

  __shared__ __align__(16) unsigned short As[2 * 4096];    // 16 KB
  __shared__ __align__(16) unsigned short Bs[2 * 8192];    // 32 KB

  const int t = threadIdx.x;
  const int lane = t & 63, wv = t >> 6;
  const int srow = t >> 2, skc = t & 3;
  const int ln31 = lane & 31, hi = lane >> 5;
  const int wr = wv >> 1, wc = wv & 1;

  // A source rows (2 groups of 64)
  const unsigned short* ap[2];
#pragma unroll
  for (int g = 0; g < 2; ++g) {
    int mr = m0 + srow + 64 * g;
    int tok;
    if (routed) {
      int s = off + (mr < count ? mr : count - 1);
      tok = slot_tok[s];
    } else {
      tok = mr;
    }
    ap[g] = XB + (size_t)tok * DMODEL + skc * 8;
  }
  // B source rows (4 groups of 64; groups 0-1 = a-cols, 2-3 = g-cols)
  const unsigned short* bp[4];
#pragma unroll
  for (int g = 0; g < 4; ++g) {
    int brow = srow + 64 * g;
    int wrow = (brow < 128) ? (n0 + brow) : (H + n0 + brow - 128);
    bp[g] = W + (size_t)wrow * DMODEL + skc * 8;
  }

  f32x16 acc_a[2][2], acc_g[2][2];
  const f32x16 z16 = {0.f,0.f,0.f,0.f,0.f,0.f,0.f,0.f,0.f,0.f,0.f,0.f,0.f,0.f,0.f,0.f};
#pragma unroll
  for (int i = 0; i < 2; ++i)
#pragma unroll
    for (int j = 0; j < 2; ++j) { acc_a[i][j] = z16; acc_g[i][j] = z16; }

  for (int kt = 0; kt < DMODEL / 64; ++kt) {
    const int kb = kt * 64;
    __syncthreads();
#pragma unroll
    for (int h = 0; h < 2; ++h) {
#pragma unroll
      for (int g = 0; g < 2; ++g)
        gl_lds16(ap[g] + kb + h * 32, &As[h * 4096 + g * 2048 + wv * 512]);
#pragma unroll
      for (int g = 0; g < 4; ++g)
        gl_lds16(bp[g] + kb + h * 32, &Bs[h * 8192 + g * 2048 + wv * 512]);
    }
    __syncthreads();
#pragma unroll
    for (int ks = 0; ks < 4; ++ks) {
      const int h = ks >> 1;
      const int ko = (ks & 1) * 16 + hi * 8;
      bf16x8 aF[2], bA[2], bG[2];
#pragma unroll
      for (int i = 0; i < 2; ++i)
        aF[i] = *(const bf16x8*)&As[h * 4096 + (wr * 64 + i * 32 + ln31) * 32 + ko];
#pragma unroll
      for (int j = 0; j < 2; ++j) {
        bA[j] = *(const bf16x8*)&Bs[h * 8192 + (wc * 64 + j * 32 + ln31) * 32 + ko];
        bG[j] = *(const bf16x8*)&Bs[h * 8192 + (128 + wc * 64 + j * 32 + ln31) * 32 + ko];
      }
#pragma unroll
      for (int i = 0; i < 2; ++i)
#pragma unroll
        for (int j = 0; j < 2; ++j) {
          acc_a[i][j] = __builtin_amdgcn_mfma_f32_32x32x16_bf16(aF[i], bA[j], acc_a[i][j], 0, 0, 0);
          acc_g[i][j] = __builtin_amdgcn_mfma_f32_32x32x16_bf16(aF[i], bG[j], acc_g[i][j], 0, 0, 0);
        }
    }
  }

  float ba[2], bg[2];
#pragma unroll
  for (int j = 0; j < 2; ++j) {
    int col = n0 + wc * 64 + j * 32 + ln31;
    ba[j] = bias[col];
    bg[j] = bias[H + col];
  }
#pragma unroll
  for (int i = 0; i < 2; ++i)
#pragma unroll
    for (int j = 0; j < 2; ++j)
#pragma unroll
      for (int reg = 0; reg < 16; ++reg) {
        // 32x32 C/D: col = lane&31, row = (reg&3) + 8*(reg>>2) + 4*(lane>>5)
        int row = wr * 64 + i * 32 + (reg & 3) + 8 * (reg >> 2) + 4 * hi;
        if (m0 + row < count) {
          int col = n0 + wc * 64 + j * 32 + ln31;
          float av = acc_a[i][j][reg] + ba[j];
          float gv = acc_g[i][j][reg] + bg[j];
          ACT[(size_t)(off + m0 + row) * H + col] = f2bf(av * gelu_exact(gv));
        }
      }
}

// ---------------- GEMM2, single launch (shared + routed), atomic combine ---
#define G2_SHARED 128   /* 16 m x 8 n */
#define G2_PER_E  128   /* 16 m x 8 n */

__global__ __launch_bounds__(256, 2)
void gemm2_all_kernel(const unsigned short* __restrict__ ACT_S,
                      const unsigned short* __restrict__ ACT_R,
                      const unsigned short* __restrict__ WSt,
                      const unsigned short* __restrict__ WEt,
                      const float* __restrict__ BSb, const float* __restrict__ BEb,
                      float* __restrict__ OUT,
                      const int* __restrict__ slot_tok, const float* __restrict__ slot_w,
                      const int* __restrict__ offs, const int* __restrict__ counts) {
  int id = blockIdx.x;
  const unsigned short* A; const unsigned short* W; const float* bias;
  int K, count, off, m0, n0, routed;
  if (id < G2_SHARED) {
    routed = 0;
    m0 = (id >> 3) * 128; n0 = (id & 7) * 128;
    A = ACT_S; W = WSt; bias = BSb; K = HS_DIM; count = N_TOK; off = 0;
  } else {
    routed = 1;
    id -= G2_SHARED;
    const int e = id / G2_PER_E, rem = id % G2_PER_E;
    m0 = (rem >> 3) * 128; n0 = (rem & 7) * 128;
    A = ACT_R; W = WEt + (size_t)e * DMODEL * HR_DIM;
    bias = BEb + (size_t)e * DMODEL; K = HR_DIM; count = counts[e]; off = offs[e];
  }
  if (m0 >= count) return;

  __shared__ __align__(16) unsigned short As[2 * 4096];    // 16 KB
  __shared__ __align__(16) unsigned short Bs[2 * 4096];    // 16 KB

  const int t = threadIdx.x;
  const int lane = t & 63, wv = t >> 6;
  const int srow = t >> 2, skc = t & 3;
  const int ln31 = lane & 31, hi = lane >> 5;
  const int wr = wv >> 1, wc = wv & 1;

  const unsigned short* ap[2];
#pragma unroll
  for (int g = 0; g < 2; ++g) {
    int mr = m0 + srow + 64 * g;
    int r = off + (mr < count ? mr : count - 1);
    ap[g] = A + (size_t)r * K + skc * 8;
  }
  const unsigned short* bp[2];
#pragma unroll
  for (int g = 0; g < 2; ++g)
    bp[g] = W + (size_t)(n0 + srow + 64 * g) * K + skc * 8;

  f32x16 acc[2][2];
  const f32x16 z16 = {0.f,0.f,0.f,0.f,0.f,0.f,0.f,0.f,0.f,0.f,0.f,0.f,0.f,0.f,0.f,0.f};
#pragma unroll
  for (int i = 0; i < 2; ++i)
#pragma unroll
    for (int j = 0; j < 2; ++j) acc[i][j] = z16;

  const int KT = K >> 6;
  for (int kt = 0; kt < KT; ++kt) {
    const int kb = kt * 64;
    __syncthreads();
#pragma unroll
    for (int h = 0; h < 2; ++h) {
#pragma unroll
      for (int g = 0; g < 2; ++g) {
        gl_lds16(ap[g] + kb + h * 32, &As[h * 4096 + g * 2048 + wv * 512]);
        gl_lds16(bp[g] + kb + h * 32, &Bs[h * 4096 + g * 2048 + wv * 512]);
      }
    }
    __syncthreads();
#pragma unroll
    for (int ks = 0; ks < 4; ++ks) {
      const int h = ks >> 1;
      const int ko = (ks & 1) * 16 + hi * 8;
      bf16x8 aF[2], bF[2];
#pragma unroll
      for (int i = 0; i < 2; ++i)
        aF[i] = *(const bf16x8*)&As[h * 4096 + (wr * 64 + i * 32 + ln31) * 32 + ko];
#pragma unroll
      for (int j = 0; j < 2; ++j)
        bF[j] = *(const bf16x8*)&Bs[h * 4096 + (wc * 64 + j * 32 + ln31) * 32 + ko];
#pragma unroll
      for (int i = 0; i < 2; ++i)
#pragma unroll
        for (int j = 0; j < 2; ++j)
          acc[i][j] = __builtin_amdgcn_mfma_f32_32x32x16_bf16(aF[i], bF[j], acc[i][j], 0, 0, 0);
    }
  }

  float bb[2];
#pragma unroll
  for (int j = 0; j < 2; ++j) bb[j] = bias[n0 + wc * 64 + j * 32 + ln31];
#pragma unroll
  for (int i = 0; i < 2; ++i)
#pragma unroll
    for (int j = 0; j < 2; ++j)
#pragma unroll
      for (int reg = 0; reg < 16; ++reg) {
        int row = wr * 64 + i * 32 + (reg & 3) + 8 * (reg >> 2) + 4 * hi;
        if (m0 + row < count) {
          int col = n0 + wc * 64 + j * 32 + ln31;
          float v = acc[i][j][reg] + bb[j];
          if (routed) {
            int s = off + m0 + row;
            atomicAdd(&OUT[(size_t)slot_tok[s] * DMODEL + col], slot_w[s] * v);
          } else {
            atomicAdd(&OUT[(size_t)(m0 + row) * DMODEL + col], v);
          }
        }
      }
}

// ---------------- launch ----------------

extern "C" void kernel_launch(void* const* d_in, const int* in_sizes, int n_in,
                              void* d_out, int out_size, void* d_ws, size_t ws_size,
                              hipStream_t stream) {
  const float* x   = (const float*)d_in[0];
  const float* Ws1 = (const float*)d_in[1];
  const float* bs1 = (const float*)d_in[2];
  const float* Ws2 = (const float*)d_in[3];
  const float* bs2 = (const float*)d_in[4];
  const float* We1 = (const float*)d_in[5];
  const float* be1 = (const float*)d_in[6];
  const float* We2 = (const float*)d_in[7];
  const float* be2 = (const float*)d_in[8];
  const float* Wr  = (const float*)d_in[9];
  const float* br  = (const float*)d_in[10];
  float* out = (float*)d_out;

  char* p = (char*)d_ws;
  int* counts  = (int*)p; p += 256;
  int* cursors = (int*)p; p += 256;
  int* offs    = (int*)p; p += 256;
  int* top_e   = (int*)p; p += (size_t)N_TOK * 2 * 4;
  float* top_w = (float*)p; p += (size_t)N_TOK * 2 * 4;
  int* slot_tok = (int*)p; p += (size_t)2 * N_TOK * 4;
  float* slot_w = (float*)p; p += (size_t)2 * N_TOK * 4;
  unsigned short* xb    = (unsigned short*)p; p += (size_t)N_TOK * DMODEL * 2;
  unsigned short* ws1t  = (unsigned short*)p; p += (size_t)2 * HS_DIM * DMODEL * 2;
  unsigned short* ws2t  = (unsigned short*)p; p += (size_t)DMODEL * HS_DIM * 2;
  unsigned short* we1t  = (unsigned short*)p; p += (size_t)NEXP * 2 * HR_DIM * DMODEL * 2;
  unsigned short* we2t  = (unsigned short*)p; p += (size_t)NEXP * DMODEL * HR_DIM * 2;
  unsigned short* act_s = (unsigned short*)p; p += (size_t)N_TOK * HS_DIM * 2;
  unsigned short* act_r = (unsigned short*)p; p += (size_t)2 * N_TOK * HR_DIM * 2;

  zero_out_kernel<<<(N_TOK * DMODEL) / 1024, 256, 0, stream>>>((float4*)out);

  // conversions
  convert_x_kernel<<<(N_TOK * DMODEL) / 2048, 256, 0, stream>>>(x, xb);
  tconv_kernel<<<dim3(2 * HS_DIM / 64, DMODEL / 64, 1), 256, 0, stream>>>(Ws1, ws1t, DMODEL, 2 * HS_DIM);
  tconv_kernel<<<dim3(DMODEL / 64, HS_DIM / 64, 1), 256, 0, stream>>>(Ws2, ws2t, HS_DIM, DMODEL);
  tconv_kernel<<<dim3(2 * HR_DIM / 64, DMODEL / 64, NEXP), 256, 0, stream>>>(We1, we1t, DMODEL, 2 * HR_DIM);
  tconv_kernel<<<dim3(DMODEL / 64, HR_DIM / 64, NEXP), 256, 0, stream>>>(We2, we2t, HR_DIM, DMODEL);

  // routing chain
  init_kernel<<<1, 64, 0, stream>>>(counts, cursors);
  router_kernel<<<N_TOK / 4, 256, 0, stream>>>(x, Wr, br, top_e, top_w, counts);
  scan_kernel<<<1, 64, 0, stream>>>(counts, offs);
  fill_kernel<<<N_TOK / 256, 256, 0, stream>>>(top_e, top_w, offs, cursors, slot_tok, slot_w);

  // GEMM1 + GEGLU (shared + all experts, one launch)
  gemm1_all_kernel<<<G1_SHARED + G1_PER_E * NEXP, 256, 0, stream>>>(
      xb, ws1t, we1t, bs1, be1, act_s, act_r, slot_tok, offs, counts);

  // GEMM2 (shared + routed, one launch, atomic accumulate into zeroed out)
  gemm2_all_kernel<<<G2_SHARED + G2_PER_E * NEXP, 256, 0, stream>>>(
      act_s, act_r, ws2t, we2t, bs2, be2, out, slot_tok, slot_w, offs, counts);
}